// Round 1
// 471.895 us; speedup vs baseline: 1.0318x; 1.0318x over previous
//
#include <hip/hip_runtime.h>
#include <cstdint>

// ---------------------------------------------------------------------------
// Attention_75093208203309 on gfx950 — round 8.
// vs R7: CL and PV move to a new 256x256-tile, 8-wave, counted-vmcnt core
// (guide T3+T4: 4-deep K-pipeline, BK=32, 4 LDS buffers = 128 KiB, one raw
// s_barrier per K-step, s_waitcnt vmcnt(8) steady-state — never a full drain
// in the main loop, setprio(1) around the MFMA cluster). CL grid = 256 blocks
// (1/CU, perfectly balanced); PV becomes split-K=4 -> 256 uniform blocks.
// G1 / qc_s (incl. S) / softmax unchanged.
// Pipeline: preps -> G1(qk,vt) -> [qc|S] -> CL256->st -> softmax -> PV256 -> reduce.
// ---------------------------------------------------------------------------

typedef __attribute__((ext_vector_type(8))) short short8;
typedef __attribute__((ext_vector_type(4))) float f32x4;
typedef __attribute__((ext_vector_type(4))) float f4v;
typedef __attribute__((ext_vector_type(4))) unsigned short u16x4;
typedef __attribute__((ext_vector_type(8))) unsigned short u16x8;

typedef unsigned short u16;
typedef unsigned char u8;

__device__ __forceinline__ u16 f2bf(float f) {
  unsigned u = __float_as_uint(f);
  u += 0x7fffu + ((u >> 16) & 1u);   // RNE
  return (u16)(u >> 16);
}
__device__ __forceinline__ float bf2f(u16 h) {
  return __uint_as_float(((unsigned)h) << 16);
}

__device__ __forceinline__ void gld16(void* lds, const void* g) {
  __builtin_amdgcn_global_load_lds(
      (__attribute__((address_space(1))) void*)g,
      (__attribute__((address_space(3))) void*)lds,
      16, 0, 0);
}

// ---------------- prep kernels ----------------

// x [4096,1024] f32 -> xs3 [4096,3072] bf16 = [hi | lo | hi]   (A-side)
__global__ void prep_x(const float* __restrict__ x, u16* __restrict__ xs3) {
  int id = blockIdx.x * 256 + threadIdx.x;       // float4 index
  int flat = id * 4;
  int n = flat >> 10, i = flat & 1023;
  f4v v = *(const f4v*)(x + (size_t)flat);
  u16x4 hi, lo;
#pragma unroll
  for (int e = 0; e < 4; e++) {
    float f = v[e];
    u16 h = f2bf(f);
    hi[e] = h;
    lo[e] = f2bf(f - bf2f(h));
  }
  size_t base = (size_t)n * 3072 + i;
  *(u16x4*)(xs3 + base) = hi;
  *(u16x4*)(xs3 + base + 1024) = lo;
  *(u16x4*)(xs3 + base + 2048) = hi;
}

// W_{q,k,v} [1024,1024] -> W3 [3072 rows, 3072] bf16 = [hi | hi | lo]  (B-side)
__global__ void prep_w(const float* __restrict__ Wq, const float* __restrict__ Wk,
                       const float* __restrict__ Wv, u16* __restrict__ W3) {
  int id = blockIdx.x * 256 + threadIdx.x;
  int flat = id * 4;
  int o = flat >> 10, i = flat & 1023;
  const float* src = (o < 1024) ? (Wq + (size_t)o * 1024)
                   : (o < 2048) ? (Wk + (size_t)(o - 1024) * 1024)
                                : (Wv + (size_t)(o - 2048) * 1024);
  f4v v = *(const f4v*)(src + i);
  u16x4 hi, lo;
#pragma unroll
  for (int e = 0; e < 4; e++) {
    u16 h = f2bf(v[e]);
    hi[e] = h;
    lo[e] = f2bf(v[e] - bf2f(h));
  }
  size_t base = (size_t)o * 3072 + i;
  *(u16x4*)(W3 + base) = hi;
  *(u16x4*)(W3 + base + 1024) = hi;
  *(u16x4*)(W3 + base + 2048) = lo;
}

__global__ void prep_bias(const float* __restrict__ bq, const float* __restrict__ bk,
                          const float* __restrict__ bv, float* __restrict__ bp) {
  int id = blockIdx.x * 256 + threadIdx.x;
  float v = (id < 1024) ? bq[id] : (id < 2048) ? bk[id - 1024] : bv[id - 2048];
  bp[id] = v;
}

// connection C [1024,1024] -> C3 [1024,3072]: C3[j] = [Ct_hi | Ct_hi | Ct_lo]
__global__ void prep_c(const float* __restrict__ C, u16* __restrict__ C3) {
  __shared__ float t[32][33];
  int lx = threadIdx.x & 31, ly = threadIdx.x >> 5;   // 32 x 8
  int i0 = blockIdx.x * 32, j0 = blockIdx.y * 32;
#pragma unroll
  for (int r = 0; r < 32; r += 8)
    t[ly + r][lx] = C[(size_t)(i0 + ly + r) * 1024 + j0 + lx];
  __syncthreads();
#pragma unroll
  for (int r = 0; r < 32; r += 8) {
    float f = t[lx][ly + r];                           // = C[i0+lx][j0+ly+r]
    u16 h = f2bf(f);
    u16 l = f2bf(f - bf2f(h));
    size_t o = (size_t)(j0 + ly + r) * 3072 + i0 + lx;
    C3[o] = h;
    C3[o + 1024] = h;
    C3[o + 2048] = l;
  }
}

// ---------------- NT GEMM core, 128x128, BK=64 + XOR bank swizzle ----------
// (unchanged R7 core — still used by G1 and merged qc|S)

struct EpiG1 {        // mode 0: q/k columns; mode 1: vt = Wv@x^T + bv
  const float* bp; u16* qs3; u16* k3; u16* vt; int mode;
  __device__ void operator()(int r, int c, float v) const {
    if (mode == 0) {
      v += bp[c];
      u16 h = f2bf(v);
      u16 l = f2bf(v - bf2f(h));
      if (c < 1024) {                     // q: A-side [hi|lo|hi]
        size_t b = (size_t)r * 3072 + c;
        qs3[b] = h; qs3[b + 1024] = l; qs3[b + 2048] = h;
      } else {                            // k: B-side [hi|hi|lo]
        size_t b = (size_t)r * 3072 + (c - 1024);
        k3[b] = h; k3[b + 1024] = h; k3[b + 2048] = l;
      }
    } else {                              // vt[r][c], r = Wv row, c = x row
      v += bp[2048 + r];
      vt[(size_t)r * 4096 + c] = f2bf(v); // coalesced in c (lane16)
    }
  }
};

struct EpiQCS {       // merged G2/S epilogue
  u16* qc3; u16* Sc; int isS;
  __device__ void operator()(int r, int c, float v) const {
    if (isS) {
      Sc[(size_t)r * 4096 + c] = f2bf(v);
    } else {
      u16 h = f2bf(v);
      u16 l = f2bf(v - bf2f(h));
      size_t b = (size_t)r * 3072 + c;
      qc3[b] = h; qc3[b + 1024] = l; qc3[b + 2048] = h;
    }
  }
};

struct EpiCL {        // CL: straight-through mask bit from fp32 accumulator
  u8* st; float b0;
  __device__ void operator()(int r, int c, float v) const {
    st[(size_t)r * 4096 + c] = (v + b0 > 0.f) ? 1 : 0;
  }
};

struct EpiPart {      // PV split-K: plain partial store
  float* part;
  __device__ void operator()(int r, int c, float v) const {
    part[(size_t)r * 1024 + c] = v;
  }
};

template <class Epi>
__device__ __forceinline__ void gemm_core(
    const u16* __restrict__ A, const u16* __restrict__ B,
    int lda, int ldb, int K, int mBase, int nBase, Epi epi) {
  __shared__ __align__(16) u16 lA[128 * 64];
  __shared__ __align__(16) u16 lB[128 * 64];
  const int tid = threadIdx.x;
  const int wave = tid >> 6, lane = tid & 63;
  const int wm = wave & 1, wn = wave >> 1;
  const int lane16 = lane & 15, quad = lane >> 4;

  const int srow = tid >> 3;
  const int gchunk = ((tid & 7) ^ (srow & 7)) * 8;
  const u16* aP = A + (size_t)(mBase + srow) * lda + gchunk;
  const u16* bP = B + (size_t)(nBase + srow) * ldb + gchunk;
  const int woff = wave * 1024;   // issue i covers rows [32i,32i+32)

  const int rsw = lane16 & 7;
  const u16* raB = lA + (wm * 64 + lane16) * 64;
  const u16* rbB = lB + (wn * 64 + lane16) * 64;

  f32x4 acc[4][4];
#pragma unroll
  for (int i = 0; i < 4; i++)
#pragma unroll
    for (int j = 0; j < 4; j++) acc[i][j] = (f32x4){0.f, 0.f, 0.f, 0.f};

  for (int k0 = 0; k0 < K; k0 += 64) {
#pragma unroll
    for (int i = 0; i < 4; i++) {
      gld16((char*)lA + i * 4096 + woff, aP + (size_t)(32 * i) * lda + k0);
      gld16((char*)lB + i * 4096 + woff, bP + (size_t)(32 * i) * ldb + k0);
    }
    __syncthreads();
    short8 af[2][4], bfr[2][4];
#pragma unroll
    for (int s = 0; s < 2; s++) {
      const int sl = (((s << 2) + quad) ^ rsw) * 8;
#pragma unroll
      for (int j = 0; j < 4; j++) {
        af[s][j]  = *(const short8*)(raB + j * 1024 + sl);
        bfr[s][j] = *(const short8*)(rbB + j * 1024 + sl);
      }
    }
#pragma unroll
    for (int s = 0; s < 2; s++)
#pragma unroll
      for (int im = 0; im < 4; im++)
#pragma unroll
        for (int in = 0; in < 4; in++)
          acc[im][in] = __builtin_amdgcn_mfma_f32_16x16x32_bf16(
              af[s][im], bfr[s][in], acc[im][in], 0, 0, 0);
    __syncthreads();
  }

#pragma unroll
  for (int im = 0; im < 4; im++)
#pragma unroll
    for (int in = 0; in < 4; in++)
#pragma unroll
      for (int i = 0; i < 4; i++) {
        int r = mBase + wm * 64 + im * 16 + quad * 4 + i;
        int c = nBase + wn * 64 + in * 16 + lane16;
        epi(r, c, acc[im][in][i]);
      }
}

// ---------------- 256x256 counted-vmcnt GEMM core (NEW, R8) ----------------
// 512 threads = 8 waves (2M x 4N), per-wave 128x64 output, BK=32.
// LDS: 4 buffers x (A[256][32] + B[256][32]) bf16 = 128 KiB, 1 block/CU.
// Pipeline depth 3: while computing tile t, tiles t+1,t+2 are landed/landing
// and t+3 is being issued. One raw s_barrier per K-step; steady-state wait is
// s_waitcnt vmcnt(8) (2 tiles in flight stay across the barrier) — never a
// full drain in the main loop (guide T3+T4). Tail peels vmcnt 8 -> 4 -> 0.
// Swizzle: phys 16B-slot = k-chunk ^ ((row>>1)&3); staged by pre-swizzling the
// global source chunk (linear global_load_lds dest), read with the same XOR.

template <class Epi>
__device__ __forceinline__ void gemm256_core(
    const u16* __restrict__ A, const u16* __restrict__ B,
    int lda, int ldb, int K, int mBase, int nBase, Epi epi) {
  __shared__ __align__(16) u16 lA[4][256 * 32];   // 64 KiB
  __shared__ __align__(16) u16 lB[4][256 * 32];   // 64 KiB
  const int tid  = threadIdx.x;                   // 0..511
  const int wave = tid >> 6, lane = tid & 63;
  const int lane16 = lane & 15, quad = lane >> 4;
  const int wm = wave >> 2, wn = wave & 3;        // 2 x 4 wave grid
  const int NT = K >> 5;                          // 32-wide K tiles (NT >= 4)

  // staging: thread t covers row (t>>2)+128i, phys slot t&3,
  // global chunk = (t&3) ^ ((row>>1)&3) = (t&3) ^ ((t>>3)&3)  (i-invariant)
  const int srow = tid >> 2;
  const int gch  = ((tid & 3) ^ ((tid >> 3) & 3)) * 8;
  const u16* aS = A + (size_t)(mBase + srow) * lda + gch;
  const u16* bS = B + (size_t)(nBase + srow) * ldb + gch;
  const size_t aStep = (size_t)128 * lda, bStep = (size_t)128 * ldb;
  const int ldsW = wave * 1024;                   // wave slice byte offset

  // reader: frag row = (wm*128 | wn*64) + 16*frag + lane16, k-chunk = quad
  const int sw   = (lane16 >> 1) & 3;
  const int aOff = (wm * 128 + lane16) * 64 + ((quad ^ sw) * 16);
  const int bOff = (wn * 64  + lane16) * 64 + ((quad ^ sw) * 16);

  f32x4 acc[8][4];
#pragma unroll
  for (int j = 0; j < 8; j++)
#pragma unroll
    for (int n = 0; n < 4; n++) acc[j][n] = (f32x4){0.f, 0.f, 0.f, 0.f};

  short8 af[8], bfr[4];

  auto stage = [&](int t) {
    const int bb = (t & 3) * 16384;
    const size_t kk = (size_t)(t << 5);
#pragma unroll
    for (int i = 0; i < 2; i++) {
      gld16((char*)lA + bb + i * 8192 + ldsW, aS + (size_t)i * aStep + kk);
      gld16((char*)lB + bb + i * 8192 + ldsW, bS + (size_t)i * bStep + kk);
    }
  };
  auto rdfrags = [&](int t) {
    const char* la = (const char*)lA + (t & 3) * 16384 + aOff;
    const char* lb = (const char*)lB + (t & 3) * 16384 + bOff;
#pragma unroll
    for (int j = 0; j < 8; j++) af[j] = *(const short8*)(la + j * 1024);
#pragma unroll
    for (int n = 0; n < 4; n++) bfr[n] = *(const short8*)(lb + n * 1024);
  };
  auto mfma32 = [&]() {
    __builtin_amdgcn_s_setprio(1);
#pragma unroll
    for (int j = 0; j < 8; j++)
#pragma unroll
      for (int n = 0; n < 4; n++)
        acc[j][n] = __builtin_amdgcn_mfma_f32_16x16x32_bf16(
            af[j], bfr[n], acc[j][n], 0, 0, 0);
    __builtin_amdgcn_s_setprio(0);
  };

  // prologue: tiles 0,1,2 in flight; wait until tile 0 landed (8 left)
  stage(0); stage(1); stage(2);
  asm volatile("s_waitcnt vmcnt(8)" ::: "memory");
  __builtin_amdgcn_sched_barrier(0);
  __builtin_amdgcn_s_barrier();
  __builtin_amdgcn_sched_barrier(0);

  int t = 0;
  for (; t + 4 <= NT; ++t) {
    rdfrags(t);
    stage(t + 3);
    // leave tiles t+2,t+3 (8 loads) in flight; t+1 landed for next step
    asm volatile("s_waitcnt vmcnt(8) lgkmcnt(0)" ::: "memory");
    __builtin_amdgcn_sched_barrier(0);
    __builtin_amdgcn_s_barrier();
    __builtin_amdgcn_sched_barrier(0);
    mfma32();
  }
  // t == NT-3: no stage; tile NT-1 (4 loads) may stay in flight
  rdfrags(t);
  asm volatile("s_waitcnt vmcnt(4) lgkmcnt(0)" ::: "memory");
  __builtin_amdgcn_sched_barrier(0);
  __builtin_amdgcn_s_barrier();
  __builtin_amdgcn_sched_barrier(0);
  mfma32();
  ++t;
  // t == NT-2: drain everything (tile NT-1 must land)
  rdfrags(t);
  asm volatile("s_waitcnt vmcnt(0) lgkmcnt(0)" ::: "memory");
  __builtin_amdgcn_sched_barrier(0);
  __builtin_amdgcn_s_barrier();
  __builtin_amdgcn_sched_barrier(0);
  mfma32();
  ++t;
  // t == NT-1: last tile, no barrier needed after
  rdfrags(t);
  asm volatile("s_waitcnt lgkmcnt(0)" ::: "memory");
  __builtin_amdgcn_sched_barrier(0);
  mfma32();

#pragma unroll
  for (int j = 0; j < 8; j++)
#pragma unroll
    for (int n = 0; n < 4; n++)
#pragma unroll
      for (int i = 0; i < 4; i++)
        epi(mBase + wm * 128 + j * 16 + quad * 4 + i,
            nBase + wn * 64 + n * 16 + lane16, acc[j][n][i]);
}

// G1, 1-D grid of 768, long blocks first (unchanged):
//   bid<512:  q,k = xs3@W3^T (K=3072), nBase=(bid&15)*128, mBase=(bid>>4)*128
//   bid>=512: vt = Wv_hi@x_hi^T (K=1024)
__global__ __launch_bounds__(256, 2) void gemm_g1(
    const u16* __restrict__ xs3, const u16* __restrict__ W3,
    const float* __restrict__ bp, u16* __restrict__ qs3,
    u16* __restrict__ k3, u16* __restrict__ vt) {
  const int bid = blockIdx.x;
  if (bid < 512) {
    gemm_core(xs3, W3, 3072, 3072, 3072, (bid >> 4) * 128, (bid & 15) * 128,
              EpiG1{bp, qs3, k3, vt, 0});
  } else {
    const int t = bid - 512;   // 256 blocks: M=1024 (x8), N=4096 (x32)
    gemm_core(W3 + (size_t)2048 * 3072, xs3, 3072, 3072, 1024,
              (t & 7) * 128, (t >> 3) * 128, EpiG1{bp, qs3, k3, vt, 1});
  }
}

// merged G2/S, 1-D grid of 1280, long blocks first (unchanged):
//   bid<256:  qc = qs3@C3^T (K=3072), nBase=(bid&7)*128, mBase=(bid>>3)*128
//   bid>=256: S = q_hi@k_hi^T (K=1024)
__global__ __launch_bounds__(256, 2) void gemm_qc_s(
    const u16* __restrict__ qs3, const u16* __restrict__ C3,
    const u16* __restrict__ k3, u16* __restrict__ qc3, u16* __restrict__ Sc) {
  const int bid = blockIdx.x;
  if (bid < 256) {
    gemm_core(qs3, C3, 3072, 3072, 3072, (bid >> 3) * 128, (bid & 7) * 128,
              EpiQCS{qc3, Sc, 0});
  } else {
    const int t = bid - 256;   // 1024 blocks: N=4096 (x32), M=4096 (x32)
    gemm_core(qs3, k3, 3072, 3072, 1024, (t >> 5) * 128, (t & 31) * 128,
              EpiQCS{qc3, Sc, 1});
  }
}

// CL = qc3 @ k3^T (K=3072) -> st bits, on the 256^2 counted-vmcnt core.
// 256 blocks = 1/CU exactly; XCD-chunked swizzle (256 % 8 == 0, bijective).
__global__ __launch_bounds__(512, 2) void gemm_cl256(
    const u16* __restrict__ qc3, const u16* __restrict__ k3,
    const float* __restrict__ bias, u8* __restrict__ st) {
  const int bid = blockIdx.x;
  const int wg = (bid & 7) * 32 + (bid >> 3);
  gemm256_core(qc3, k3, 3072, 3072, 3072, (wg >> 4) * 256, (wg & 15) * 256,
               EpiCL{st, bias[0]});
}

// PV on the 256^2 core, split-K=4: bid>>6 = K-slice z, rem: 16 m x 4 n tiles.
// parts: z=0,1 -> p01 + z*4M ; z=2,3 -> p23 + (z&1)*4M.
__global__ __launch_bounds__(512, 2) void gemm_pv256(
    const u16* __restrict__ P, const u16* __restrict__ vt,
    float* __restrict__ p01, float* __restrict__ p23) {
  const int bid = blockIdx.x;            // 0..255
  const int z = bid >> 6, rem = bid & 63;
  float* base = ((z < 2) ? p01 : p23) + (size_t)(z & 1) * (4096ull * 1024ull);
  const size_t kOff = (size_t)z * 1024;
  gemm256_core(P + kOff, vt + kOff, 4096, 4096, 1024,
               (rem >> 2) * 256, (rem & 3) * 256, EpiPart{base});
}

// out = (1-bm)*x + bm*(p0+p1+p2+p3)
__global__ void reduce_out(const float* __restrict__ x, const float* __restrict__ bm,
                           const float* __restrict__ p01, const float* __restrict__ p23,
                           float* __restrict__ out) {
  int id = blockIdx.x * 256 + threadIdx.x;
  int flat = id * 4;
  int r = flat >> 10;
  float b = bm[r];
  const size_t SL = (size_t)4096 * 1024;
  f4v xv = *(const f4v*)(x + (size_t)flat);
  f4v a0 = *(const f4v*)(p01 + (size_t)flat);
  f4v a1 = *(const f4v*)(p01 + SL + flat);
  f4v a2 = *(const f4v*)(p23 + (size_t)flat);
  f4v a3 = *(const f4v*)(p23 + SL + flat);
  f4v o;
#pragma unroll
  for (int e = 0; e < 4; e++)
    o[e] = b * ((a0[e] + a1[e]) + (a2[e] + a3[e])) + (1.0f - b) * xv[e];
  *(f4v*)(out + (size_t)flat) = o;
}

// ---------------- mask + softmax (unchanged) ----------------
// logits = S/32 - 10000*(1 - am - st*lm); P = softmax(row).
__global__ __launch_bounds__(256) void mask_softmax(
    const u16* __restrict__ Sc, const u8* __restrict__ st,
    const float* __restrict__ am, const float* __restrict__ lm,
    u16* __restrict__ P) {
  const int n = blockIdx.x, tid = threadIdx.x;
  const int lane = tid & 63, wave = tid >> 6;
  const u16* Srow = Sc + (size_t)n * 4096;
  const u8* Trow = st + (size_t)n * 4096;
  const float* Arow = am + (size_t)n * 4096;
  const float* Lrow = lm + (size_t)n * 4096;

  float lg[16];
  float mx = -3.4e38f;
#pragma unroll
  for (int j = 0; j < 2; j++) {
    int base = (tid + 256 * j) * 8;
    u16x8 s8 = *(const u16x8*)(Srow + base);
    unsigned long long t8 = *(const unsigned long long*)(Trow + base);
    f4v a0 = *(const f4v*)(Arow + base), a1 = *(const f4v*)(Arow + base + 4);
    f4v l0 = *(const f4v*)(Lrow + base), l1 = *(const f4v*)(Lrow + base + 4);
#pragma unroll
    for (int e = 0; e < 8; e++) {
      float stv = ((t8 >> (8 * e)) & 1ull) ? 1.f : 0.f;
      float a = (e < 4) ? a0[e] : a1[e - 4];
      float l = (e < 4) ? l0[e] : l1[e - 4];
      float mv = a + stv * l;
      float v = bf2f(s8[e]) * 0.03125f - 10000.f * (1.f - mv);
      lg[j * 8 + e] = v;
      mx = fmaxf(mx, v);
    }
  }
#pragma unroll
  for (int o = 32; o; o >>= 1) mx = fmaxf(mx, __shfl_xor(mx, o));
  __shared__ float smax[4], ssum[4];
  if (lane == 0) smax[wave] = mx;
  __syncthreads();
  mx = fmaxf(fmaxf(smax[0], smax[1]), fmaxf(smax[2], smax[3]));

  float sum = 0.f;
#pragma unroll
  for (int i = 0; i < 16; i++) { lg[i] = __expf(lg[i] - mx); sum += lg[i]; }
#pragma unroll
  for (int o = 32; o; o >>= 1) sum += __shfl_xor(sum, o);
  if (lane == 0) ssum[wave] = sum;
  __syncthreads();
  float inv = 1.f / (ssum[0] + ssum[1] + ssum[2] + ssum[3]);

  u16* Pr = P + (size_t)n * 4096;
#pragma unroll
  for (int j = 0; j < 2; j++) {
    int base = (tid + 256 * j) * 8;
    u16x8 o8;
#pragma unroll
    for (int e = 0; e < 8; e++) o8[e] = f2bf(lg[j * 8 + e] * inv);
    *(u16x8*)(Pr + base) = o8;
  }
}

// ---------------- launch ----------------

extern "C" void kernel_launch(void* const* d_in, const int* in_sizes, int n_in,
                              void* d_out, int out_size, void* d_ws, size_t ws_size,
                              hipStream_t stream) {
  const float* x    = (const float*)d_in[0];
  const float* am   = (const float*)d_in[1];
  const float* lm   = (const float*)d_in[2];
  const float* bm   = (const float*)d_in[3];
  const float* Wq   = (const float*)d_in[4];
  const float* bq   = (const float*)d_in[5];
  const float* Wk   = (const float*)d_in[6];
  const float* bk   = (const float*)d_in[7];
  const float* Wv   = (const float*)d_in[8];
  const float* bv   = (const float*)d_in[9];
  const float* Cc   = (const float*)d_in[10];
  const float* bias = (const float*)d_in[11];
  float* out = (float*)d_out;
  char* ws = (char*)d_ws;

  if (ws_size < 0xB010000) return;  // ~176 MB scratch

  u16*  xs3 = (u16*) (ws + 0x0000000);  // 24 MB [x_hi|x_lo|x_hi]
  u16*  W3  = (u16*) (ws + 0x1800000);  // 18 MB [W_hi|W_hi|W_lo]
  u16*  C3  = (u16*) (ws + 0x2A00000);  //  6 MB [Ct_hi|Ct_hi|Ct_lo]
  float* bp = (float*)(ws + 0x3000000); // 12 KB
  u16*  qs3 = (u16*) (ws + 0x3010000);  // 24 MB [q_hi|q_lo|q_hi]
  u16*  qc3 = (u16*) (ws + 0x4810000);  // 24 MB [qc_hi|qc_lo|qc_hi]
  u16*  k3  = (u16*) (ws + 0x6010000);  // 24 MB [k_hi|k_hi|k_lo]
  u16*  vt  = (u16*) (ws + 0x7810000);  //  8 MB v^T [1024,4096]
  u16*  Sc  = (u16*) (ws + 0x8010000);  // 32 MB bf16 S
  u8*   st  = (u8*)  (ws + 0xA010000);  // 16 MB straight-through bits
  u16*  P   = (u16*) (ws + 0x0000000);  // 32 MB overlay (xs3/W3-head dead)
  // PV partials (written after softmax consumed Sc; qc3/k3 dead after CL):
  float* parts01 = (float*)(ws + 0x4810000); // 32 MB overlay (qc3 + k3-head)
  float* parts23 = (float*)(ws + 0x8010000); // 32 MB overlay (Sc)

  prep_x   <<<4096, 256, 0, stream>>>(x, xs3);
  prep_w   <<<3072, 256, 0, stream>>>(Wq, Wk, Wv, W3);
  prep_bias<<<12,   256, 0, stream>>>(bq, bk, bv, bp);
  prep_c   <<<dim3(32, 32), 256, 0, stream>>>(Cc, C3);

  // G1: q,k = xs3 @ W3^T (K=3072, bid<512) | vt = Wv@x^T (K=1024, bid>=512)
  gemm_g1<<<768, 256, 0, stream>>>(xs3, W3, bp, qs3, k3, vt);
  // merged: qc = qs3 @ C3^T (K=3072, bid<256) | S = q_hi @ k_hi^T (K=1024)
  gemm_qc_s<<<1280, 256, 0, stream>>>(qs3, C3, k3, qc3, Sc);
  // CL = qc3 @ k3^T (K=3072) -> st bits (256^2 counted-vmcnt core)
  gemm_cl256<<<256, 512, 0, stream>>>(qc3, k3, bias, st);
  // mask + softmax -> P (bf16)
  mask_softmax<<<4096, 256, 0, stream>>>(Sc, st, am, lm, P);
  // PV: parts[z] = P[:,z-slice] @ vt[:,z-slice]^T (256^2 core, split-K=4)
  gemm_pv256<<<256, 512, 0, stream>>>(P, vt, parts01, parts23);
  // out = (1-bm)x + bm*(p0+p1+p2+p3)
  reduce_out<<<4096, 256, 0, stream>>>(x, bm, parts01, parts23, out);
}

// Round 2
// 456.485 us; speedup vs baseline: 1.0666x; 1.0338x over previous
//
#include <hip/hip_runtime.h>
#include <cstdint>

// ---------------------------------------------------------------------------
// Attention_75093208203309 on gfx950 — round 9.
// vs R8: boundary-mask row compaction. out = bm*attn@v + (1-bm)*x with bm
// ~50% zero -> rows with bm==0 need NO q/qc/S/CL/softmax/PV work. A prefix-sum
// prep builds idx[] (compact->orig row map) + cnt; the whole q-chain runs in
// compact row space (gather at q-staging, scatter at PV epilogue). Grids are
// worst-case sized; blocks early-exit via device-side cnt. Arithmetic for
// surviving rows is bitwise identical to R8. CL/PV return to the 128^2 core
// (at cnt~2048 it load-balances better than the 256^2 core: 512 blocks @2/CU
// vs 128 @1/CU); the 256-core's lockstep fix is deferred to next round.
// Pipeline: prep_bm -> preps -> G1(k,q,vt) -> [qc|S] -> CL -> softmax -> PV -> reduce.
// ---------------------------------------------------------------------------

typedef __attribute__((ext_vector_type(8))) short short8;
typedef __attribute__((ext_vector_type(4))) float f32x4;
typedef __attribute__((ext_vector_type(4))) float f4v;
typedef __attribute__((ext_vector_type(4))) unsigned short u16x4;
typedef __attribute__((ext_vector_type(8))) unsigned short u16x8;

typedef unsigned short u16;
typedef unsigned char u8;

__device__ __forceinline__ u16 f2bf(float f) {
  unsigned u = __float_as_uint(f);
  u += 0x7fffu + ((u >> 16) & 1u);   // RNE
  return (u16)(u >> 16);
}
__device__ __forceinline__ float bf2f(u16 h) {
  return __uint_as_float(((unsigned)h) << 16);
}

__device__ __forceinline__ void gld16(void* lds, const void* g) {
  __builtin_amdgcn_global_load_lds(
      (__attribute__((address_space(1))) void*)g,
      (__attribute__((address_space(3))) void*)lds,
      16, 0, 0);
}

// ---------------- prep kernels ----------------

// bm [4096] -> idx[] = compact list of rows with bm!=0 (sorted), cnt.
// idx[cnt..4095] padded with 0 so gathered staging reads stay in bounds.
__global__ void prep_bm(const float* __restrict__ bm, int* __restrict__ idx,
                        int* __restrict__ cntp) {
  __shared__ int ps[1024];
  const int t = threadIdx.x;
  int loc[4];
  int c = 0;
#pragma unroll
  for (int e = 0; e < 4; e++) {
    int r = t * 4 + e;
    if (bm[r] != 0.0f) loc[c++] = r;
  }
  ps[t] = c;
  __syncthreads();
  for (int off = 1; off < 1024; off <<= 1) {
    int v = (t >= off) ? ps[t - off] : 0;
    __syncthreads();
    ps[t] += v;
    __syncthreads();
  }
  int base = ps[t] - c;
  for (int i = 0; i < c; i++) idx[base + i] = loc[i];
  int cnt = ps[1023];
  if (t == 0) cntp[0] = cnt;
  for (int r = cnt + t; r < 4096; r += 1024) idx[r] = 0;
}

// x [4096,1024] f32 -> xs3 [4096,3072] bf16 = [hi | lo | hi]   (A-side)
__global__ void prep_x(const float* __restrict__ x, u16* __restrict__ xs3) {
  int id = blockIdx.x * 256 + threadIdx.x;       // float4 index
  int flat = id * 4;
  int n = flat >> 10, i = flat & 1023;
  f4v v = *(const f4v*)(x + (size_t)flat);
  u16x4 hi, lo;
#pragma unroll
  for (int e = 0; e < 4; e++) {
    float f = v[e];
    u16 h = f2bf(f);
    hi[e] = h;
    lo[e] = f2bf(f - bf2f(h));
  }
  size_t base = (size_t)n * 3072 + i;
  *(u16x4*)(xs3 + base) = hi;
  *(u16x4*)(xs3 + base + 1024) = lo;
  *(u16x4*)(xs3 + base + 2048) = hi;
}

// W_{q,k,v} [1024,1024] -> W3 [3072 rows, 3072] bf16 = [hi | hi | lo]  (B-side)
__global__ void prep_w(const float* __restrict__ Wq, const float* __restrict__ Wk,
                       const float* __restrict__ Wv, u16* __restrict__ W3) {
  int id = blockIdx.x * 256 + threadIdx.x;
  int flat = id * 4;
  int o = flat >> 10, i = flat & 1023;
  const float* src = (o < 1024) ? (Wq + (size_t)o * 1024)
                   : (o < 2048) ? (Wk + (size_t)(o - 1024) * 1024)
                                : (Wv + (size_t)(o - 2048) * 1024);
  f4v v = *(const f4v*)(src + i);
  u16x4 hi, lo;
#pragma unroll
  for (int e = 0; e < 4; e++) {
    u16 h = f2bf(v[e]);
    hi[e] = h;
    lo[e] = f2bf(v[e] - bf2f(h));
  }
  size_t base = (size_t)o * 3072 + i;
  *(u16x4*)(W3 + base) = hi;
  *(u16x4*)(W3 + base + 1024) = hi;
  *(u16x4*)(W3 + base + 2048) = lo;
}

__global__ void prep_bias(const float* __restrict__ bq, const float* __restrict__ bk,
                          const float* __restrict__ bv, float* __restrict__ bp) {
  int id = blockIdx.x * 256 + threadIdx.x;
  float v = (id < 1024) ? bq[id] : (id < 2048) ? bk[id - 1024] : bv[id - 2048];
  bp[id] = v;
}

// connection C [1024,1024] -> C3 [1024,3072]: C3[j] = [Ct_hi | Ct_hi | Ct_lo]
__global__ void prep_c(const float* __restrict__ C, u16* __restrict__ C3) {
  __shared__ float t[32][33];
  int lx = threadIdx.x & 31, ly = threadIdx.x >> 5;   // 32 x 8
  int i0 = blockIdx.x * 32, j0 = blockIdx.y * 32;
#pragma unroll
  for (int r = 0; r < 32; r += 8)
    t[ly + r][lx] = C[(size_t)(i0 + ly + r) * 1024 + j0 + lx];
  __syncthreads();
#pragma unroll
  for (int r = 0; r < 32; r += 8) {
    float f = t[lx][ly + r];                           // = C[i0+lx][j0+ly+r]
    u16 h = f2bf(f);
    u16 l = f2bf(f - bf2f(h));
    size_t o = (size_t)(j0 + ly + r) * 3072 + i0 + lx;
    C3[o] = h;
    C3[o + 1024] = h;
    C3[o + 2048] = l;
  }
}

// ---------------- NT GEMM core, 128x128, BK=64 + XOR bank swizzle ----------
// C[M,N] = A[M,K] @ B[N,K]^T, bf16 in, fp32 accum, 128x128 tile, 4 waves,
// 16x16x32 bf16 MFMA, global_load_lds width 16, 64-deep K-step.
// Optional ridx: A-side row gather (compact-M GEMMs read A rows idx[m]).
// LDS swizzle: row r k-chunk c at slot c ^ (r&7); 0 bank conflicts (verified).

struct EpiQ {         // q: A-side layout [hi|lo|hi], compact rows
  const float* bp; u16* qs3;
  __device__ void operator()(int r, int c, float v) const {
    v += bp[c];
    u16 h = f2bf(v);
    u16 l = f2bf(v - bf2f(h));
    size_t b = (size_t)r * 3072 + c;
    qs3[b] = h; qs3[b + 1024] = l; qs3[b + 2048] = h;
  }
};

struct EpiK {         // k: B-side layout [hi|hi|lo], full rows
  const float* bp; u16* k3;
  __device__ void operator()(int r, int c, float v) const {
    v += bp[1024 + c];
    u16 h = f2bf(v);
    u16 l = f2bf(v - bf2f(h));
    size_t b = (size_t)r * 3072 + c;
    k3[b] = h; k3[b + 1024] = h; k3[b + 2048] = l;
  }
};

struct EpiVt {        // vt[r][c], r = Wv row (d), c = x row
  const float* bp; u16* vt;
  __device__ void operator()(int r, int c, float v) const {
    v += bp[2048 + r];
    vt[(size_t)r * 4096 + c] = f2bf(v);
  }
};

struct EpiQCS {       // merged G2/S epilogue (compact rows)
  u16* qc3; u16* Sc; int isS;
  __device__ void operator()(int r, int c, float v) const {
    if (isS) {
      Sc[(size_t)r * 4096 + c] = f2bf(v);
    } else {
      u16 h = f2bf(v);
      u16 l = f2bf(v - bf2f(h));
      size_t b = (size_t)r * 3072 + c;
      qc3[b] = h; qc3[b + 1024] = l; qc3[b + 2048] = h;
    }
  }
};

struct EpiCL {        // CL: straight-through mask bit (compact rows)
  u8* st; float b0;
  __device__ void operator()(int r, int c, float v) const {
    st[(size_t)r * 4096 + c] = (v + b0 > 0.f) ? 1 : 0;
  }
};

struct EpiPart {      // PV split-K: scatter partial to original row space
  float* part; const int* idx; int cnt;
  __device__ void operator()(int r, int c, float v) const {
    if (r < cnt) part[(size_t)idx[r] * 1024 + c] = v;
  }
};

template <class Epi>
__device__ __forceinline__ void gemm_core(
    const u16* __restrict__ A, const u16* __restrict__ B,
    int lda, int ldb, int K, int mBase, int nBase,
    const int* __restrict__ ridx, Epi epi) {
  __shared__ __align__(16) u16 lA[128 * 64];
  __shared__ __align__(16) u16 lB[128 * 64];
  const int tid = threadIdx.x;
  const int wave = tid >> 6, lane = tid & 63;
  const int wm = wave & 1, wn = wave >> 1;
  const int lane16 = lane & 15, quad = lane >> 4;

  // staging: thread t stages rows (t>>3)+32i, phys slot (t&7),
  // global chunk = (t&7) ^ (row&7)   (row&7 invariant under +32)
  const int srow = tid >> 3;
  const int gchunk = ((tid & 7) ^ (srow & 7)) * 8;
  const u16* aPi[4];
#pragma unroll
  for (int i = 0; i < 4; i++) {
    int row = mBase + srow + 32 * i;
    int g = ridx ? ridx[row] : row;
    aPi[i] = A + (size_t)g * lda + gchunk;
  }
  const u16* bP = B + (size_t)(nBase + srow) * ldb + gchunk;
  const int woff = wave * 1024;   // issue i covers rows [32i,32i+32)

  const int rsw = lane16 & 7;
  const u16* raB = lA + (wm * 64 + lane16) * 64;
  const u16* rbB = lB + (wn * 64 + lane16) * 64;

  f32x4 acc[4][4];
#pragma unroll
  for (int i = 0; i < 4; i++)
#pragma unroll
    for (int j = 0; j < 4; j++) acc[i][j] = (f32x4){0.f, 0.f, 0.f, 0.f};

  for (int k0 = 0; k0 < K; k0 += 64) {
#pragma unroll
    for (int i = 0; i < 4; i++) {
      gld16((char*)lA + i * 4096 + woff, aPi[i] + k0);
      gld16((char*)lB + i * 4096 + woff, bP + (size_t)(32 * i) * ldb + k0);
    }
    __syncthreads();
    short8 af[2][4], bfr[2][4];
#pragma unroll
    for (int s = 0; s < 2; s++) {
      const int sl = (((s << 2) + quad) ^ rsw) * 8;
#pragma unroll
      for (int j = 0; j < 4; j++) {
        af[s][j]  = *(const short8*)(raB + j * 1024 + sl);
        bfr[s][j] = *(const short8*)(rbB + j * 1024 + sl);
      }
    }
#pragma unroll
    for (int s = 0; s < 2; s++)
#pragma unroll
      for (int im = 0; im < 4; im++)
#pragma unroll
        for (int in = 0; in < 4; in++)
          acc[im][in] = __builtin_amdgcn_mfma_f32_16x16x32_bf16(
              af[s][im], bfr[s][in], acc[im][in], 0, 0, 0);
    __syncthreads();
  }

#pragma unroll
  for (int im = 0; im < 4; im++)
#pragma unroll
    for (int in = 0; in < 4; in++)
#pragma unroll
      for (int i = 0; i < 4; i++) {
        int r = mBase + wm * 64 + im * 16 + quad * 4 + i;
        int c = nBase + wn * 64 + in * 16 + lane16;
        epi(r, c, acc[im][in][i]);
      }
}

// G1, 1-D grid of 768, long/always-on blocks first:
//   bid<256:        k = xs3@Wk^T (K=3072, full M): m=(bid>>3)*128, n=(bid&7)*128
//   bid in [256,512): q = gather(xs3)@Wq^T (K=3072, compact M, early-exit)
//   bid>=512:       vt = Wv_hi@x_hi^T (K=1024)
__global__ __launch_bounds__(256, 2) void gemm_g1(
    const u16* __restrict__ xs3, const u16* __restrict__ W3,
    const float* __restrict__ bp, u16* __restrict__ qs3,
    u16* __restrict__ k3, u16* __restrict__ vt,
    const int* __restrict__ idx, const int* __restrict__ cntp) {
  const int bid = blockIdx.x;
  if (bid < 256) {
    gemm_core(xs3, W3 + (size_t)1024 * 3072, 3072, 3072, 3072,
              (bid >> 3) * 128, (bid & 7) * 128, nullptr, EpiK{bp, k3});
  } else if (bid < 512) {
    const int t = bid - 256;
    const int mBase = (t >> 3) * 128;
    if (mBase >= cntp[0]) return;
    gemm_core(xs3, W3, 3072, 3072, 3072, mBase, (t & 7) * 128, idx,
              EpiQ{bp, qs3});
  } else {
    const int t = bid - 512;   // 256 blocks: M=1024 (x8), N=4096 (x32)
    gemm_core(W3 + (size_t)2048 * 3072, xs3, 3072, 3072, 1024,
              (t & 7) * 128, (t >> 3) * 128, nullptr, EpiVt{bp, vt});
  }
}

// merged G2/S, 1-D grid of 1280, long blocks first, compact M, early-exit:
//   bid<256:  qc = qs3@C3^T (K=3072): m=(bid>>3)*128 (exit if >=cnt), n=(bid&7)*128
//   bid>=256: S = q_hi@k_hi^T (K=1024): t=bid-256, m=(t>>5)*128 (exit), n=(t&31)*128
__global__ __launch_bounds__(256, 2) void gemm_qc_s(
    const u16* __restrict__ qs3, const u16* __restrict__ C3,
    const u16* __restrict__ k3, u16* __restrict__ qc3, u16* __restrict__ Sc,
    const int* __restrict__ cntp) {
  const int bid = blockIdx.x;
  const int cnt = cntp[0];
  if (bid < 256) {
    const int mBase = (bid >> 3) * 128;
    if (mBase >= cnt) return;
    gemm_core(qs3, C3, 3072, 3072, 3072, mBase, (bid & 7) * 128, nullptr,
              EpiQCS{qc3, Sc, 0});
  } else {
    const int t = bid - 256;
    const int mBase = (t >> 5) * 128;
    if (mBase >= cnt) return;
    gemm_core(qs3, k3, 3072, 3072, 1024, mBase, (t & 31) * 128, nullptr,
              EpiQCS{qc3, Sc, 1});
  }
}

// CL = qc3 @ k3^T (K=3072) -> st bits; compact M, 1-D grid 1024, early-exit.
__global__ __launch_bounds__(256, 2) void gemm_cl(
    const u16* __restrict__ qc3, const u16* __restrict__ k3,
    const float* __restrict__ bias, u8* __restrict__ st,
    const int* __restrict__ cntp) {
  const int bid = blockIdx.x;
  const int mBase = (bid >> 5) * 128;
  if (mBase >= cntp[0]) return;
  gemm_core(qc3, k3, 3072, 3072, 3072, mBase, (bid & 31) * 128, nullptr,
            EpiCL{st, bias[0]});
}

// PV split-K=4: 1-D grid 1024: z=bid>>8 (K in [1024z,1024z+1024)),
// rem=bid&255: m=(rem>>3)*128 (exit if >=cnt), n=(rem&7)*128.
// Partials scattered to original row space (rows with bm==0 never written).
__global__ __launch_bounds__(256, 2) void gemm_pv(
    const u16* __restrict__ P, const u16* __restrict__ vt,
    float* __restrict__ p01, float* __restrict__ p23,
    const int* __restrict__ idx, const int* __restrict__ cntp) {
  const int bid = blockIdx.x;
  const int z = bid >> 8, rem = bid & 255;
  const int cnt = cntp[0];
  const int mBase = (rem >> 3) * 128;
  if (mBase >= cnt) return;
  float* base = ((z < 2) ? p01 : p23) + (size_t)(z & 1) * (4096ull * 1024ull);
  const size_t kOff = (size_t)z * 1024;
  gemm_core(P + kOff, vt + kOff, 4096, 4096, 1024, mBase, (rem & 7) * 128,
            nullptr, EpiPart{base, idx, cnt});
}

// out = (1-bm)*x + bm*(p0+p1+p2+p3); one row per block -> uniform branch,
// bm==0 rows skip the partial loads entirely (they hold junk for those rows).
__global__ void reduce_out(const float* __restrict__ x, const float* __restrict__ bm,
                           const float* __restrict__ p01, const float* __restrict__ p23,
                           float* __restrict__ out) {
  int id = blockIdx.x * 256 + threadIdx.x;
  int flat = id * 4;
  int r = flat >> 10;
  float b = bm[r];
  f4v xv = *(const f4v*)(x + (size_t)flat);
  f4v o;
  if (b != 0.0f) {
    const size_t SL = (size_t)4096 * 1024;
    f4v a0 = *(const f4v*)(p01 + (size_t)flat);
    f4v a1 = *(const f4v*)(p01 + SL + flat);
    f4v a2 = *(const f4v*)(p23 + (size_t)flat);
    f4v a3 = *(const f4v*)(p23 + SL + flat);
#pragma unroll
    for (int e = 0; e < 4; e++)
      o[e] = b * ((a0[e] + a1[e]) + (a2[e] + a3[e])) + (1.0f - b) * xv[e];
  } else {
    o = xv;
  }
  *(f4v*)(out + (size_t)flat) = o;
}

// ---------------- mask + softmax (compact rows, am/lm gathered) ------------
// logits = S/32 - 10000*(1 - am - st*lm); P = softmax(row).
__global__ __launch_bounds__(256) void mask_softmax(
    const u16* __restrict__ Sc, const u8* __restrict__ st,
    const float* __restrict__ am, const float* __restrict__ lm,
    u16* __restrict__ P, const int* __restrict__ idx,
    const int* __restrict__ cntp) {
  const int n = blockIdx.x, tid = threadIdx.x;
  if (n >= cntp[0]) return;
  const int orow = idx[n];
  const int lane = tid & 63, wave = tid >> 6;
  const u16* Srow = Sc + (size_t)n * 4096;
  const u8* Trow = st + (size_t)n * 4096;
  const float* Arow = am + (size_t)orow * 4096;
  const float* Lrow = lm + (size_t)orow * 4096;

  float lg[16];
  float mx = -3.4e38f;
#pragma unroll
  for (int j = 0; j < 2; j++) {
    int base = (tid + 256 * j) * 8;
    u16x8 s8 = *(const u16x8*)(Srow + base);
    unsigned long long t8 = *(const unsigned long long*)(Trow + base);
    f4v a0 = *(const f4v*)(Arow + base), a1 = *(const f4v*)(Arow + base + 4);
    f4v l0 = *(const f4v*)(Lrow + base), l1 = *(const f4v*)(Lrow + base + 4);
#pragma unroll
    for (int e = 0; e < 8; e++) {
      float stv = ((t8 >> (8 * e)) & 1ull) ? 1.f : 0.f;
      float a = (e < 4) ? a0[e] : a1[e - 4];
      float l = (e < 4) ? l0[e] : l1[e - 4];
      float mv = a + stv * l;
      float v = bf2f(s8[e]) * 0.03125f - 10000.f * (1.f - mv);
      lg[j * 8 + e] = v;
      mx = fmaxf(mx, v);
    }
  }
#pragma unroll
  for (int o = 32; o; o >>= 1) mx = fmaxf(mx, __shfl_xor(mx, o));
  __shared__ float smax[4], ssum[4];
  if (lane == 0) smax[wave] = mx;
  __syncthreads();
  mx = fmaxf(fmaxf(smax[0], smax[1]), fmaxf(smax[2], smax[3]));

  float sum = 0.f;
#pragma unroll
  for (int i = 0; i < 16; i++) { lg[i] = __expf(lg[i] - mx); sum += lg[i]; }
#pragma unroll
  for (int o = 32; o; o >>= 1) sum += __shfl_xor(sum, o);
  if (lane == 0) ssum[wave] = sum;
  __syncthreads();
  float inv = 1.f / (ssum[0] + ssum[1] + ssum[2] + ssum[3]);

  u16* Pr = P + (size_t)n * 4096;
#pragma unroll
  for (int j = 0; j < 2; j++) {
    int base = (tid + 256 * j) * 8;
    u16x8 o8;
#pragma unroll
    for (int e = 0; e < 8; e++) o8[e] = f2bf(lg[j * 8 + e] * inv);
    *(u16x8*)(Pr + base) = o8;
  }
}

// ---------------- launch ----------------

extern "C" void kernel_launch(void* const* d_in, const int* in_sizes, int n_in,
                              void* d_out, int out_size, void* d_ws, size_t ws_size,
                              hipStream_t stream) {
  const float* x    = (const float*)d_in[0];
  const float* am   = (const float*)d_in[1];
  const float* lm   = (const float*)d_in[2];
  const float* bm   = (const float*)d_in[3];
  const float* Wq   = (const float*)d_in[4];
  const float* bq   = (const float*)d_in[5];
  const float* Wk   = (const float*)d_in[6];
  const float* bk   = (const float*)d_in[7];
  const float* Wv   = (const float*)d_in[8];
  const float* bv   = (const float*)d_in[9];
  const float* Cc   = (const float*)d_in[10];
  const float* bias = (const float*)d_in[11];
  float* out = (float*)d_out;
  char* ws = (char*)d_ws;

  if (ws_size < 0xB010000) return;  // ~176 MB scratch

  u16*  xs3 = (u16*) (ws + 0x0000000);  // 24 MB [x_hi|x_lo|x_hi]
  u16*  W3  = (u16*) (ws + 0x1800000);  // 18 MB [W_hi|W_hi|W_lo]
  u16*  C3  = (u16*) (ws + 0x2A00000);  //  6 MB [Ct_hi|Ct_hi|Ct_lo]
  float* bp = (float*)(ws + 0x3000000); // 12 KB
  int*  idx = (int*)  (ws + 0x3004000); // 16 KB compact->orig row map
  int*  cnt = (int*)  (ws + 0x3008000); //  4 B  number of bm!=0 rows
  u16*  qs3 = (u16*) (ws + 0x3010000);  // 24 MB [q_hi|q_lo|q_hi]  (compact)
  u16*  qc3 = (u16*) (ws + 0x4810000);  // 24 MB [qc_hi|qc_lo|qc_hi] (compact)
  u16*  k3  = (u16*) (ws + 0x6010000);  // 24 MB [k_hi|k_hi|k_lo]  (full)
  u16*  vt  = (u16*) (ws + 0x7810000);  //  8 MB v^T [1024,4096]   (full)
  u16*  Sc  = (u16*) (ws + 0x8010000);  // 32 MB bf16 S            (compact)
  u8*   st  = (u8*)  (ws + 0xA010000);  // 16 MB straight-through  (compact)
  u16*  P   = (u16*) (ws + 0x0000000);  // 32 MB overlay (xs3/W3-head dead)
  // PV partials, original row space (qc3/k3-head and Sc dead by then):
  float* parts01 = (float*)(ws + 0x4810000); // 32 MB overlay (qc3 + k3-head)
  float* parts23 = (float*)(ws + 0x8010000); // 32 MB overlay (Sc)

  prep_bm  <<<1, 1024, 0, stream>>>(bm, idx, cnt);
  prep_x   <<<4096, 256, 0, stream>>>(x, xs3);
  prep_w   <<<3072, 256, 0, stream>>>(Wq, Wk, Wv, W3);
  prep_bias<<<12,   256, 0, stream>>>(bq, bk, bv, bp);
  prep_c   <<<dim3(32, 32), 256, 0, stream>>>(Cc, C3);

  // G1: k (full) | q (compact, gathered) | vt
  gemm_g1<<<768, 256, 0, stream>>>(xs3, W3, bp, qs3, k3, vt, idx, cnt);
  // merged: qc = qs3 @ C3^T (K=3072) | S = q_hi @ k_hi^T (K=1024)  (compact M)
  gemm_qc_s<<<1280, 256, 0, stream>>>(qs3, C3, k3, qc3, Sc, cnt);
  // CL = qc3 @ k3^T (K=3072) -> st bits  (compact M)
  gemm_cl<<<1024, 256, 0, stream>>>(qc3, k3, bias, st, cnt);
  // mask + softmax -> P (bf16, compact rows; am/lm gathered via idx)
  mask_softmax<<<4096, 256, 0, stream>>>(Sc, st, am, lm, P, idx, cnt);
  // PV: parts[z] = P @ vt^T over K-quarters, scattered to original rows
  gemm_pv<<<1024, 256, 0, stream>>>(P, vt, parts01, parts23, idx, cnt);
  // out = (1-bm)x + bm*(p0+p1+p2+p3)
  reduce_out<<<4096, 256, 0, stream>>>(x, bm, parts01, parts23, out);
}

// Round 3
// 417.853 us; speedup vs baseline: 1.1652x; 1.0925x over previous
//
#include <hip/hip_runtime.h>
#include <cstdint>

// ---------------------------------------------------------------------------
// Attention_75093208203309 on gfx950 — round 10.
// vs R9: fix the gemm_g1 LDS explosion. gemm_core is __forceinline__, and R9
// gave gemm_g1 three call sites with three Epi types -> 3x 32KB LDS = 96KB ->
// 1 block/CU -> MfmaUtil 16%, 115us. All GEMM kernels are now single-call-site
// with unified mode-carrying epilogues (one instantiation = one 32KB LDS
// allocation). No arithmetic change vs R9 (bitwise-identical outputs).
// Pipeline: prep_bm -> preps -> G1(k|q|vt) -> [qc|S] -> CL -> softmax -> PV -> reduce.
// ---------------------------------------------------------------------------

typedef __attribute__((ext_vector_type(8))) short short8;
typedef __attribute__((ext_vector_type(4))) float f32x4;
typedef __attribute__((ext_vector_type(4))) float f4v;
typedef __attribute__((ext_vector_type(4))) unsigned short u16x4;
typedef __attribute__((ext_vector_type(8))) unsigned short u16x8;

typedef unsigned short u16;
typedef unsigned char u8;

__device__ __forceinline__ u16 f2bf(float f) {
  unsigned u = __float_as_uint(f);
  u += 0x7fffu + ((u >> 16) & 1u);   // RNE
  return (u16)(u >> 16);
}
__device__ __forceinline__ float bf2f(u16 h) {
  return __uint_as_float(((unsigned)h) << 16);
}

__device__ __forceinline__ void gld16(void* lds, const void* g) {
  __builtin_amdgcn_global_load_lds(
      (__attribute__((address_space(1))) void*)g,
      (__attribute__((address_space(3))) void*)lds,
      16, 0, 0);
}

// ---------------- prep kernels ----------------

// bm [4096] -> idx[] = compact list of rows with bm!=0 (sorted), cnt.
// idx[cnt..4095] padded with 0 so gathered staging reads stay in bounds.
__global__ void prep_bm(const float* __restrict__ bm, int* __restrict__ idx,
                        int* __restrict__ cntp) {
  __shared__ int ps[1024];
  const int t = threadIdx.x;
  int loc[4];
  int c = 0;
#pragma unroll
  for (int e = 0; e < 4; e++) {
    int r = t * 4 + e;
    if (bm[r] != 0.0f) loc[c++] = r;
  }
  ps[t] = c;
  __syncthreads();
  for (int off = 1; off < 1024; off <<= 1) {
    int v = (t >= off) ? ps[t - off] : 0;
    __syncthreads();
    ps[t] += v;
    __syncthreads();
  }
  int base = ps[t] - c;
  for (int i = 0; i < c; i++) idx[base + i] = loc[i];
  int cnt = ps[1023];
  if (t == 0) cntp[0] = cnt;
  for (int r = cnt + t; r < 4096; r += 1024) idx[r] = 0;
}

// x [4096,1024] f32 -> xs3 [4096,3072] bf16 = [hi | lo | hi]   (A-side)
__global__ void prep_x(const float* __restrict__ x, u16* __restrict__ xs3) {
  int id = blockIdx.x * 256 + threadIdx.x;       // float4 index
  int flat = id * 4;
  int n = flat >> 10, i = flat & 1023;
  f4v v = *(const f4v*)(x + (size_t)flat);
  u16x4 hi, lo;
#pragma unroll
  for (int e = 0; e < 4; e++) {
    float f = v[e];
    u16 h = f2bf(f);
    hi[e] = h;
    lo[e] = f2bf(f - bf2f(h));
  }
  size_t base = (size_t)n * 3072 + i;
  *(u16x4*)(xs3 + base) = hi;
  *(u16x4*)(xs3 + base + 1024) = lo;
  *(u16x4*)(xs3 + base + 2048) = hi;
}

// W_{q,k,v} [1024,1024] -> W3 [3072 rows, 3072] bf16 = [hi | hi | lo]  (B-side)
__global__ void prep_w(const float* __restrict__ Wq, const float* __restrict__ Wk,
                       const float* __restrict__ Wv, u16* __restrict__ W3) {
  int id = blockIdx.x * 256 + threadIdx.x;
  int flat = id * 4;
  int o = flat >> 10, i = flat & 1023;
  const float* src = (o < 1024) ? (Wq + (size_t)o * 1024)
                   : (o < 2048) ? (Wk + (size_t)(o - 1024) * 1024)
                                : (Wv + (size_t)(o - 2048) * 1024);
  f4v v = *(const f4v*)(src + i);
  u16x4 hi, lo;
#pragma unroll
  for (int e = 0; e < 4; e++) {
    u16 h = f2bf(v[e]);
    hi[e] = h;
    lo[e] = f2bf(v[e] - bf2f(h));
  }
  size_t base = (size_t)o * 3072 + i;
  *(u16x4*)(W3 + base) = hi;
  *(u16x4*)(W3 + base + 1024) = hi;
  *(u16x4*)(W3 + base + 2048) = lo;
}

__global__ void prep_bias(const float* __restrict__ bq, const float* __restrict__ bk,
                          const float* __restrict__ bv, float* __restrict__ bp) {
  int id = blockIdx.x * 256 + threadIdx.x;
  float v = (id < 1024) ? bq[id] : (id < 2048) ? bk[id - 1024] : bv[id - 2048];
  bp[id] = v;
}

// connection C [1024,1024] -> C3 [1024,3072]: C3[j] = [Ct_hi | Ct_hi | Ct_lo]
__global__ void prep_c(const float* __restrict__ C, u16* __restrict__ C3) {
  __shared__ float t[32][33];
  int lx = threadIdx.x & 31, ly = threadIdx.x >> 5;   // 32 x 8
  int i0 = blockIdx.x * 32, j0 = blockIdx.y * 32;
#pragma unroll
  for (int r = 0; r < 32; r += 8)
    t[ly + r][lx] = C[(size_t)(i0 + ly + r) * 1024 + j0 + lx];
  __syncthreads();
#pragma unroll
  for (int r = 0; r < 32; r += 8) {
    float f = t[lx][ly + r];                           // = C[i0+lx][j0+ly+r]
    u16 h = f2bf(f);
    u16 l = f2bf(f - bf2f(h));
    size_t o = (size_t)(j0 + ly + r) * 3072 + i0 + lx;
    C3[o] = h;
    C3[o + 1024] = h;
    C3[o + 2048] = l;
  }
}

// ---------------- NT GEMM core, 128x128, BK=64 + XOR bank swizzle ----------
// C[M,N] = A[M,K] @ B[N,K]^T, bf16 in, fp32 accum, 128x128 tile, 4 waves,
// 16x16x32 bf16 MFMA, global_load_lds width 16, 64-deep K-step.
// Optional ridx: A-side row gather (compact-M GEMMs read A rows idx[m]).
// LDS swizzle: row r k-chunk c at slot c ^ (r&7); 0 bank conflicts (verified).
// NOTE: gemm_core is __forceinline__ with static __shared__ — each *call site*
// gets its own 32KB LDS allocation. Every kernel below must have exactly ONE
// call site (mode flags inside the epilogue), or occupancy dies (R9 lesson).

struct EpiG1 {        // mode 0: k (B-side [hi|hi|lo]); 1: q (A-side [hi|lo|hi]);
                      // mode 2: vt[r][c] = (Wv@x^T + bv), r=d, c=x-row
  const float* bp; u16* qs3; u16* k3; u16* vt; int mode;
  __device__ void operator()(int r, int c, float v) const {
    if (mode == 0) {
      v += bp[1024 + c];
      u16 h = f2bf(v);
      u16 l = f2bf(v - bf2f(h));
      size_t b = (size_t)r * 3072 + c;
      k3[b] = h; k3[b + 1024] = h; k3[b + 2048] = l;
    } else if (mode == 1) {
      v += bp[c];
      u16 h = f2bf(v);
      u16 l = f2bf(v - bf2f(h));
      size_t b = (size_t)r * 3072 + c;
      qs3[b] = h; qs3[b + 1024] = l; qs3[b + 2048] = h;
    } else {
      v += bp[2048 + r];
      vt[(size_t)r * 4096 + c] = f2bf(v);
    }
  }
};

struct EpiQCS {       // merged G2/S epilogue (compact rows)
  u16* qc3; u16* Sc; int isS;
  __device__ void operator()(int r, int c, float v) const {
    if (isS) {
      Sc[(size_t)r * 4096 + c] = f2bf(v);
    } else {
      u16 h = f2bf(v);
      u16 l = f2bf(v - bf2f(h));
      size_t b = (size_t)r * 3072 + c;
      qc3[b] = h; qc3[b + 1024] = l; qc3[b + 2048] = h;
    }
  }
};

struct EpiCL {        // CL: straight-through mask bit (compact rows)
  u8* st; float b0;
  __device__ void operator()(int r, int c, float v) const {
    st[(size_t)r * 4096 + c] = (v + b0 > 0.f) ? 1 : 0;
  }
};

struct EpiPart {      // PV split-K: scatter partial to original row space
  float* part; const int* idx; int cnt;
  __device__ void operator()(int r, int c, float v) const {
    if (r < cnt) part[(size_t)idx[r] * 1024 + c] = v;
  }
};

template <class Epi>
__device__ __forceinline__ void gemm_core(
    const u16* __restrict__ A, const u16* __restrict__ B,
    int lda, int ldb, int K, int mBase, int nBase,
    const int* __restrict__ ridx, Epi epi) {
  __shared__ __align__(16) u16 lA[128 * 64];
  __shared__ __align__(16) u16 lB[128 * 64];
  const int tid = threadIdx.x;
  const int wave = tid >> 6, lane = tid & 63;
  const int wm = wave & 1, wn = wave >> 1;
  const int lane16 = lane & 15, quad = lane >> 4;

  // staging: thread t stages rows (t>>3)+32i, phys slot (t&7),
  // global chunk = (t&7) ^ (row&7)   (row&7 invariant under +32)
  const int srow = tid >> 3;
  const int gchunk = ((tid & 7) ^ (srow & 7)) * 8;
  const u16* aPi[4];
#pragma unroll
  for (int i = 0; i < 4; i++) {
    int row = mBase + srow + 32 * i;
    int g = ridx ? ridx[row] : row;
    aPi[i] = A + (size_t)g * lda + gchunk;
  }
  const u16* bP = B + (size_t)(nBase + srow) * ldb + gchunk;
  const int woff = wave * 1024;   // issue i covers rows [32i,32i+32)

  const int rsw = lane16 & 7;
  const u16* raB = lA + (wm * 64 + lane16) * 64;
  const u16* rbB = lB + (wn * 64 + lane16) * 64;

  f32x4 acc[4][4];
#pragma unroll
  for (int i = 0; i < 4; i++)
#pragma unroll
    for (int j = 0; j < 4; j++) acc[i][j] = (f32x4){0.f, 0.f, 0.f, 0.f};

  for (int k0 = 0; k0 < K; k0 += 64) {
#pragma unroll
    for (int i = 0; i < 4; i++) {
      gld16((char*)lA + i * 4096 + woff, aPi[i] + k0);
      gld16((char*)lB + i * 4096 + woff, bP + (size_t)(32 * i) * ldb + k0);
    }
    __syncthreads();
    short8 af[2][4], bfr[2][4];
#pragma unroll
    for (int s = 0; s < 2; s++) {
      const int sl = (((s << 2) + quad) ^ rsw) * 8;
#pragma unroll
      for (int j = 0; j < 4; j++) {
        af[s][j]  = *(const short8*)(raB + j * 1024 + sl);
        bfr[s][j] = *(const short8*)(rbB + j * 1024 + sl);
      }
    }
#pragma unroll
    for (int s = 0; s < 2; s++)
#pragma unroll
      for (int im = 0; im < 4; im++)
#pragma unroll
        for (int in = 0; in < 4; in++)
          acc[im][in] = __builtin_amdgcn_mfma_f32_16x16x32_bf16(
              af[s][im], bfr[s][in], acc[im][in], 0, 0, 0);
    __syncthreads();
  }

#pragma unroll
  for (int im = 0; im < 4; im++)
#pragma unroll
    for (int in = 0; in < 4; in++)
#pragma unroll
      for (int i = 0; i < 4; i++) {
        int r = mBase + wm * 64 + im * 16 + quad * 4 + i;
        int c = nBase + wn * 64 + in * 16 + lane16;
        epi(r, c, acc[im][in][i]);
      }
}

// G1, 1-D grid of 768, long/always-on blocks first, ONE gemm_core call site:
//   bid<256:        k = xs3@Wk^T (K=3072, full M): m=(bid>>3)*128, n=(bid&7)*128
//   bid in [256,512): q = gather(xs3)@Wq^T (K=3072, compact M, early-exit)
//   bid>=512:       vt = Wv_hi@x_hi^T (K=1024)
__global__ __launch_bounds__(256, 2) void gemm_g1(
    const u16* __restrict__ xs3, const u16* __restrict__ W3,
    const float* __restrict__ bp, u16* __restrict__ qs3,
    u16* __restrict__ k3, u16* __restrict__ vt,
    const int* __restrict__ idx, const int* __restrict__ cntp) {
  const int bid = blockIdx.x;
  const u16 *A, *B;
  const int* rx = nullptr;
  int K, mB, nB, mode;
  if (bid < 256) {
    A = xs3; B = W3 + (size_t)1024 * 3072; K = 3072;
    mB = (bid >> 3) * 128; nB = (bid & 7) * 128; mode = 0;
  } else if (bid < 512) {
    const int t = bid - 256;
    mB = (t >> 3) * 128;
    if (mB >= cntp[0]) return;
    A = xs3; B = W3; K = 3072; nB = (t & 7) * 128; rx = idx; mode = 1;
  } else {
    const int t = bid - 512;   // 256 blocks: M=1024 (x8), N=4096 (x32)
    A = W3 + (size_t)2048 * 3072; B = xs3; K = 1024;
    mB = (t & 7) * 128; nB = (t >> 3) * 128; mode = 2;
  }
  gemm_core(A, B, 3072, 3072, K, mB, nB, rx, EpiG1{bp, qs3, k3, vt, mode});
}

// merged G2/S, 1-D grid of 1280, compact M, early-exit, ONE call site:
//   bid<256:  qc = qs3@C3^T (K=3072): m=(bid>>3)*128, n=(bid&7)*128
//   bid>=256: S = q_hi@k_hi^T (K=1024): t=bid-256, m=(t>>5)*128, n=(t&31)*128
__global__ __launch_bounds__(256, 2) void gemm_qc_s(
    const u16* __restrict__ qs3, const u16* __restrict__ C3,
    const u16* __restrict__ k3, u16* __restrict__ qc3, u16* __restrict__ Sc,
    const int* __restrict__ cntp) {
  const int bid = blockIdx.x;
  const int cnt = cntp[0];
  const u16* B;
  int K, mB, nB, isS;
  if (bid < 256) {
    mB = (bid >> 3) * 128;
    if (mB >= cnt) return;
    B = C3; K = 3072; nB = (bid & 7) * 128; isS = 0;
  } else {
    const int t = bid - 256;
    mB = (t >> 5) * 128;
    if (mB >= cnt) return;
    B = k3; K = 1024; nB = (t & 31) * 128; isS = 1;
  }
  gemm_core(qs3, B, 3072, 3072, K, mB, nB, nullptr, EpiQCS{qc3, Sc, isS});
}

// CL = qc3 @ k3^T (K=3072) -> st bits; compact M, 1-D grid 1024, early-exit.
__global__ __launch_bounds__(256, 2) void gemm_cl(
    const u16* __restrict__ qc3, const u16* __restrict__ k3,
    const float* __restrict__ bias, u8* __restrict__ st,
    const int* __restrict__ cntp) {
  const int bid = blockIdx.x;
  const int mBase = (bid >> 5) * 128;
  if (mBase >= cntp[0]) return;
  gemm_core(qc3, k3, 3072, 3072, 3072, mBase, (bid & 31) * 128, nullptr,
            EpiCL{st, bias[0]});
}

// PV split-K=4: 1-D grid 1024: z=bid>>8 (K in [1024z,1024z+1024)),
// rem=bid&255: m=(rem>>3)*128 (exit if >=cnt), n=(rem&7)*128.
// Partials scattered to original row space (rows with bm==0 never written).
__global__ __launch_bounds__(256, 2) void gemm_pv(
    const u16* __restrict__ P, const u16* __restrict__ vt,
    float* __restrict__ p01, float* __restrict__ p23,
    const int* __restrict__ idx, const int* __restrict__ cntp) {
  const int bid = blockIdx.x;
  const int z = bid >> 8, rem = bid & 255;
  const int cnt = cntp[0];
  const int mBase = (rem >> 3) * 128;
  if (mBase >= cnt) return;
  float* base = ((z < 2) ? p01 : p23) + (size_t)(z & 1) * (4096ull * 1024ull);
  const size_t kOff = (size_t)z * 1024;
  gemm_core(P + kOff, vt + kOff, 4096, 4096, 1024, mBase, (rem & 7) * 128,
            nullptr, EpiPart{base, idx, cnt});
}

// out = (1-bm)*x + bm*(p0+p1+p2+p3); bm==0 rows skip partial loads.
__global__ void reduce_out(const float* __restrict__ x, const float* __restrict__ bm,
                           const float* __restrict__ p01, const float* __restrict__ p23,
                           float* __restrict__ out) {
  int id = blockIdx.x * 256 + threadIdx.x;
  int flat = id * 4;
  int r = flat >> 10;
  float b = bm[r];
  f4v xv = *(const f4v*)(x + (size_t)flat);
  f4v o;
  if (b != 0.0f) {
    const size_t SL = (size_t)4096 * 1024;
    f4v a0 = *(const f4v*)(p01 + (size_t)flat);
    f4v a1 = *(const f4v*)(p01 + SL + flat);
    f4v a2 = *(const f4v*)(p23 + (size_t)flat);
    f4v a3 = *(const f4v*)(p23 + SL + flat);
#pragma unroll
    for (int e = 0; e < 4; e++)
      o[e] = b * ((a0[e] + a1[e]) + (a2[e] + a3[e])) + (1.0f - b) * xv[e];
  } else {
    o = xv;
  }
  *(f4v*)(out + (size_t)flat) = o;
}

// ---------------- mask + softmax (compact rows, am/lm gathered) ------------
// logits = S/32 - 10000*(1 - am - st*lm); P = softmax(row).
__global__ __launch_bounds__(256) void mask_softmax(
    const u16* __restrict__ Sc, const u8* __restrict__ st,
    const float* __restrict__ am, const float* __restrict__ lm,
    u16* __restrict__ P, const int* __restrict__ idx,
    const int* __restrict__ cntp) {
  const int n = blockIdx.x, tid = threadIdx.x;
  if (n >= cntp[0]) return;
  const int orow = idx[n];
  const int lane = tid & 63, wave = tid >> 6;
  const u16* Srow = Sc + (size_t)n * 4096;
  const u8* Trow = st + (size_t)n * 4096;
  const float* Arow = am + (size_t)orow * 4096;
  const float* Lrow = lm + (size_t)orow * 4096;

  float lg[16];
  float mx = -3.4e38f;
#pragma unroll
  for (int j = 0; j < 2; j++) {
    int base = (tid + 256 * j) * 8;
    u16x8 s8 = *(const u16x8*)(Srow + base);
    unsigned long long t8 = *(const unsigned long long*)(Trow + base);
    f4v a0 = *(const f4v*)(Arow + base), a1 = *(const f4v*)(Arow + base + 4);
    f4v l0 = *(const f4v*)(Lrow + base), l1 = *(const f4v*)(Lrow + base + 4);
#pragma unroll
    for (int e = 0; e < 8; e++) {
      float stv = ((t8 >> (8 * e)) & 1ull) ? 1.f : 0.f;
      float a = (e < 4) ? a0[e] : a1[e - 4];
      float l = (e < 4) ? l0[e] : l1[e - 4];
      float mv = a + stv * l;
      float v = bf2f(s8[e]) * 0.03125f - 10000.f * (1.f - mv);
      lg[j * 8 + e] = v;
      mx = fmaxf(mx, v);
    }
  }
#pragma unroll
  for (int o = 32; o; o >>= 1) mx = fmaxf(mx, __shfl_xor(mx, o));
  __shared__ float smax[4], ssum[4];
  if (lane == 0) smax[wave] = mx;
  __syncthreads();
  mx = fmaxf(fmaxf(smax[0], smax[1]), fmaxf(smax[2], smax[3]));

  float sum = 0.f;
#pragma unroll
  for (int i = 0; i < 16; i++) { lg[i] = __expf(lg[i] - mx); sum += lg[i]; }
#pragma unroll
  for (int o = 32; o; o >>= 1) sum += __shfl_xor(sum, o);
  if (lane == 0) ssum[wave] = sum;
  __syncthreads();
  float inv = 1.f / (ssum[0] + ssum[1] + ssum[2] + ssum[3]);

  u16* Pr = P + (size_t)n * 4096;
#pragma unroll
  for (int j = 0; j < 2; j++) {
    int base = (tid + 256 * j) * 8;
    u16x8 o8;
#pragma unroll
    for (int e = 0; e < 8; e++) o8[e] = f2bf(lg[j * 8 + e] * inv);
    *(u16x8*)(Pr + base) = o8;
  }
}

// ---------------- launch ----------------

extern "C" void kernel_launch(void* const* d_in, const int* in_sizes, int n_in,
                              void* d_out, int out_size, void* d_ws, size_t ws_size,
                              hipStream_t stream) {
  const float* x    = (const float*)d_in[0];
  const float* am   = (const float*)d_in[1];
  const float* lm   = (const float*)d_in[2];
  const float* bm   = (const float*)d_in[3];
  const float* Wq   = (const float*)d_in[4];
  const float* bq   = (const float*)d_in[5];
  const float* Wk   = (const float*)d_in[6];
  const float* bk   = (const float*)d_in[7];
  const float* Wv   = (const float*)d_in[8];
  const float* bv   = (const float*)d_in[9];
  const float* Cc   = (const float*)d_in[10];
  const float* bias = (const float*)d_in[11];
  float* out = (float*)d_out;
  char* ws = (char*)d_ws;

  if (ws_size < 0xB010000) return;  // ~176 MB scratch

  u16*  xs3 = (u16*) (ws + 0x0000000);  // 24 MB [x_hi|x_lo|x_hi]
  u16*  W3  = (u16*) (ws + 0x1800000);  // 18 MB [W_hi|W_hi|W_lo]
  u16*  C3  = (u16*) (ws + 0x2A00000);  //  6 MB [Ct_hi|Ct_hi|Ct_lo]
  float* bp = (float*)(ws + 0x3000000); // 12 KB
  int*  idx = (int*)  (ws + 0x3004000); // 16 KB compact->orig row map
  int*  cnt = (int*)  (ws + 0x3008000); //  4 B  number of bm!=0 rows
  u16*  qs3 = (u16*) (ws + 0x3010000);  // 24 MB [q_hi|q_lo|q_hi]  (compact)
  u16*  qc3 = (u16*) (ws + 0x4810000);  // 24 MB [qc_hi|qc_lo|qc_hi] (compact)
  u16*  k3  = (u16*) (ws + 0x6010000);  // 24 MB [k_hi|k_hi|k_lo]  (full)
  u16*  vt  = (u16*) (ws + 0x7810000);  //  8 MB v^T [1024,4096]   (full)
  u16*  Sc  = (u16*) (ws + 0x8010000);  // 32 MB bf16 S            (compact)
  u8*   st  = (u8*)  (ws + 0xA010000);  // 16 MB straight-through  (compact)
  u16*  P   = (u16*) (ws + 0x0000000);  // 32 MB overlay (xs3/W3-head dead)
  // PV partials, original row space (qc3/k3-head and Sc dead by then):
  float* parts01 = (float*)(ws + 0x4810000); // 32 MB overlay (qc3 + k3-head)
  float* parts23 = (float*)(ws + 0x8010000); // 32 MB overlay (Sc)

  prep_bm  <<<1, 1024, 0, stream>>>(bm, idx, cnt);
  prep_x   <<<4096, 256, 0, stream>>>(x, xs3);
  prep_w   <<<3072, 256, 0, stream>>>(Wq, Wk, Wv, W3);
  prep_bias<<<12,   256, 0, stream>>>(bq, bk, bv, bp);
  prep_c   <<<dim3(32, 32), 256, 0, stream>>>(Cc, C3);

  // G1: k (full) | q (compact, gathered) | vt   (one call site inside)
  gemm_g1<<<768, 256, 0, stream>>>(xs3, W3, bp, qs3, k3, vt, idx, cnt);
  // merged: qc = qs3 @ C3^T (K=3072) | S = q_hi @ k_hi^T (K=1024)  (compact M)
  gemm_qc_s<<<1280, 256, 0, stream>>>(qs3, C3, k3, qc3, Sc, cnt);
  // CL = qc3 @ k3^T (K=3072) -> st bits  (compact M)
  gemm_cl<<<1024, 256, 0, stream>>>(qc3, k3, bias, st, cnt);
  // mask + softmax -> P (bf16, compact rows; am/lm gathered via idx)
  mask_softmax<<<4096, 256, 0, stream>>>(Sc, st, am, lm, P, idx, cnt);
  // PV: parts[z] = P @ vt^T over K-quarters, scattered to original rows
  gemm_pv<<<1024, 256, 0, stream>>>(P, vt, parts01, parts23, idx, cnt);
  // out = (1-bm)x + bm*(p0+p1+p2+p3)
  reduce_out<<<4096, 256, 0, stream>>>(x, bm, parts01, parts23, out);
}